// Round 12
// baseline (149.713 us; speedup 1.0000x reference)
//
#include <hip/hip_runtime.h>
#include <math.h>

typedef __attribute__((ext_vector_type(8))) short  short8;    // 8 bf16 = 4 VGPRs
typedef __attribute__((ext_vector_type(4))) float  floatx4;   // MFMA C/D

#define MFMA16(a, b, c) __builtin_amdgcn_mfma_f32_16x16x32_bf16(a, b, c, 0, 0, 0)

constexpr int NSEQ = 2048;
constexpr int DIN  = 768;
constexpr int NH   = 12;
constexpr float QSCALE = 0.18033688011112042f;  // log2(e)/8

constexpr int PK = 72;   // 144 B rows, 16 B-aligned for b128

__device__ __forceinline__ ushort f2bf(float f) {   // RNE fp32 -> bf16
    unsigned u = __float_as_uint(f);
    u += 0x7FFF + ((u >> 16) & 1);
    return (ushort)(u >> 16);
}
__device__ __forceinline__ float bf2f(ushort u) {
    return __uint_as_float(((unsigned)u) << 16);
}
__device__ __forceinline__ unsigned cvt_pk_bf16(float lo, float hi) {
    unsigned r;
    asm("v_cvt_pk_bf16_f32 %0, %1, %2" : "=v"(r) : "v"(lo), "v"(hi));
    return r;
}
// pack 8 f32 -> 8 bf16 (RNE) with 4 instructions
__device__ __forceinline__ short8 pk8(float4 a, float4 b) {
    union { unsigned u[4]; short8 s; } r;
    r.u[0] = cvt_pk_bf16(a.x, a.y);
    r.u[1] = cvt_pk_bf16(a.z, a.w);
    r.u[2] = cvt_pk_bf16(b.x, b.y);
    r.u[3] = cvt_pk_bf16(b.z, b.w);
    return r.s;
}
// LDS-only barrier: orders ds ops across the block WITHOUT draining vmcnt,
// so register-prefetch global loads stay in flight across the barrier.
__device__ __forceinline__ void bar_lds() {
    asm volatile("s_waitcnt lgkmcnt(0)" ::: "memory");
    __builtin_amdgcn_s_barrier();
}

// -----------------------------------------------------------------------------
// Kernel 1: h = x @ Wq^T, fused f32->bf16, DOUBLE-BUFFERED LDS (r10 verified).
// BM=64 x BN=64, grid (64,12) = 768 blocks, 3/CU. UNCHANGED this round.
// (Staging writes here are row-per-8-lanes -> already bank-conflict-free.)
// -----------------------------------------------------------------------------
__global__ __launch_bounds__(256, 3)
void qkv_mfma(const float* __restrict__ x, const float* __restrict__ Wq,
              ushort* __restrict__ h)
{
    __shared__ ushort As[2][64 * PK];    // [buf][row][k]
    __shared__ ushort Bs[2][64 * PK];    // [buf][col][k]

    const int tid  = threadIdx.x;
    const int w    = tid >> 6;
    const int lane = tid & 63;
    const int m    = lane & 15;
    const int quad = lane >> 4;
    const int r0   = blockIdx.x * 64;
    const int c0   = blockIdx.y * 64;
    const int mrow0 = (w & 1) * 32;
    const int ncol0 = (w >> 1) * 32;

    const int srow = tid >> 3;          // staging row 0..31 (+32 for i=1)
    const int scol = (tid & 7) * 8;     // staging col (8 floats)

    floatx4 C[2][2] = {};
    float4 arf[2][2], brf[2][2];        // f32 prefetch regs (8 floats per i)

    #pragma unroll
    for (int i = 0; i < 2; ++i) {
        const float* ax = x  + (size_t)(r0 + srow + i * 32) * DIN + scol;
        const float* bx = Wq + (size_t)(c0 + srow + i * 32) * DIN + scol;
        arf[i][0] = ((const float4*)ax)[0]; arf[i][1] = ((const float4*)ax)[1];
        brf[i][0] = ((const float4*)bx)[0]; brf[i][1] = ((const float4*)bx)[1];
    }
    #pragma unroll
    for (int i = 0; i < 2; ++i) {
        *(short8*)&As[0][(srow + i * 32) * PK + scol] = pk8(arf[i][0], arf[i][1]);
        *(short8*)&Bs[0][(srow + i * 32) * PK + scol] = pk8(brf[i][0], brf[i][1]);
    }
    #pragma unroll
    for (int i = 0; i < 2; ++i) {
        const float* ax = x  + (size_t)(r0 + srow + i * 32) * DIN + 64 + scol;
        const float* bx = Wq + (size_t)(c0 + srow + i * 32) * DIN + 64 + scol;
        arf[i][0] = ((const float4*)ax)[0]; arf[i][1] = ((const float4*)ax)[1];
        brf[i][0] = ((const float4*)bx)[0]; brf[i][1] = ((const float4*)bx)[1];
    }
    bar_lds();

    for (int kk = 0; kk < 12; ++kk) {
        const int cur = kk & 1;

        #pragma unroll
        for (int kt2 = 0; kt2 < 2; ++kt2) {
            short8 a0 = *(const short8*)&As[cur][(mrow0 + m)      * PK + kt2 * 32 + quad * 8];
            short8 a1 = *(const short8*)&As[cur][(mrow0 + 16 + m) * PK + kt2 * 32 + quad * 8];
            short8 b0 = *(const short8*)&Bs[cur][(ncol0 + m)      * PK + kt2 * 32 + quad * 8];
            short8 b1 = *(const short8*)&Bs[cur][(ncol0 + 16 + m) * PK + kt2 * 32 + quad * 8];
            C[0][0] = MFMA16(a0, b0, C[0][0]);
            C[0][1] = MFMA16(a0, b1, C[0][1]);
            C[1][0] = MFMA16(a1, b0, C[1][0]);
            C[1][1] = MFMA16(a1, b1, C[1][1]);
        }

        if (kk + 1 < 12) {
            const int nxt = cur ^ 1;
            #pragma unroll
            for (int i = 0; i < 2; ++i) {
                *(short8*)&As[nxt][(srow + i * 32) * PK + scol] = pk8(arf[i][0], arf[i][1]);
                *(short8*)&Bs[nxt][(srow + i * 32) * PK + scol] = pk8(brf[i][0], brf[i][1]);
            }
            if (kk + 2 < 12) {
                const int k0 = (kk + 2) * 64;
                #pragma unroll
                for (int i = 0; i < 2; ++i) {
                    const float* ax = x  + (size_t)(r0 + srow + i * 32) * DIN + k0 + scol;
                    const float* bx = Wq + (size_t)(c0 + srow + i * 32) * DIN + k0 + scol;
                    arf[i][0] = ((const float4*)ax)[0]; arf[i][1] = ((const float4*)ax)[1];
                    brf[i][0] = ((const float4*)bx)[0]; brf[i][1] = ((const float4*)bx)[1];
                }
            }
            bar_lds();                  // ONE barrier per iteration
        }
    }

    #pragma unroll
    for (int mt = 0; mt < 2; ++mt)
        #pragma unroll
        for (int nt = 0; nt < 2; ++nt) {
            int cg = c0 + ncol0 + nt * 16 + m;
            int head = cg >> 6, d = cg & 63;
            #pragma unroll
            for (int r = 0; r < 4; ++r) {
                int rg = r0 + mrow0 + mt * 16 + quad * 4 + r;
                int b = rg >> 11, q = rg & 2047;
                h[((size_t)(b * NH + head) * NSEQ + q) * 64 + d] = f2bf(C[mt][nt][r]);
            }
        }
}

// -----------------------------------------------------------------------------
// Kernel 2: causal flash attention — r10 pair-block skeleton (balanced 33
// tile-units/block, 4 waves qsub x khalf, double-buffered, 1 bar/iter) with
// the LDS-ISSUE fix (r11 falsified occupancy; DS-op arithmetic fits all
// rounds):
//  (a) Vt staged via a SECOND global load (lane = 8 keys x 2 d, coalesced):
//      pack in-register, write V^T as 2 ds_write_b128 (was 16 ds_write_b32),
//      conflict-free (8-lane groups cover full rows across all 32 banks).
//  (b) Ks XOR-swizzle (idx ^= ((row>>3)&7)<<3, write + ka-read): kills the
//      4x-serialized b128 stage-writes (the 6.2M conflict cycles).
// Staging DS cost per block-tile: ~755 -> ~190 cyc.
// -----------------------------------------------------------------------------
__global__ __launch_bounds__(256, 3)
void attn_mfma(const ushort* __restrict__ h, float* __restrict__ out)
{
    __shared__ ushort Ks[2][64 * PK];   // [buf][key][d]  (XOR-swizzled)
    __shared__ ushort Vt[2][64 * PK];   // [buf][d][key]  (linear)
    __shared__ ushort Ps[2][16 * PK];   // [qsub][q][key]

    const int tid  = threadIdx.x;
    const int w    = tid >> 6;          // 0..3
    const int lane = tid & 63;
    const int m    = lane & 15;
    const int quad = lane >> 4;
    const int qsub = w & 1;             // q-subtile 0/1 (16 q each)
    const int khalf= w >> 1;            // key-half 0/1 (32 keys each)

    const int p  = blockIdx.x;          // pair id 0..31
    const int bh = blockIdx.y;          // 0..23
    const ushort* __restrict__ Hh = h + (size_t)bh * NSEQ * 64;
    ushort* Psw = Ps[qsub];

    // row-load lane mapping (Ks): 2 adjacent key rows x 8 d
    const int kr2  = (tid & 31) * 2;
    const int db   = (tid >> 5) * 8;
    // col-load lane mapping (Vt): 8 keys x 2 d, coalesced 4B/lane
    const int d0   = (tid >> 3) * 2;
    const int kr8  = (tid & 7) * 8;

    // swizzled Ks write indices (XOR on ushort-idx bits 3..5 = byte bits 4..6)
    const int ksw0 = kr2       * PK + (db ^ (((kr2 >> 3) & 7) << 3));
    const int ksw1 = (kr2 + 1) * PK + (db ^ ((((kr2 + 1) >> 3) & 7) << 3));
    const int vti0 = d0       * PK + kr8;
    const int vti1 = (d0 + 1) * PK + kr8;

    float* Om = (float*)&Ks[0][0];      // merge scratch [2][64][pitch 17]
    float* Lm = Om + 2 * 64 * 17;       // [2][16]

#define STAGE_TILE(B) do {                                                     \
    *(short8*)&Ks[B][ksw0] = pre0;                                             \
    *(short8*)&Ks[B][ksw1] = pre1;                                             \
    uint4 ve, vo;                                                              \
    ve.x = (vc[0] & 0xFFFFu) | (vc[1] << 16);                                  \
    vo.x = (vc[0] >> 16)     | (vc[1] & 0xFFFF0000u);                          \
    ve.y = (vc[2] & 0xFFFFu) | (vc[3] << 16);                                  \
    vo.y = (vc[2] >> 16)     | (vc[3] & 0xFFFF0000u);                          \
    ve.z = (vc[4] & 0xFFFFu) | (vc[5] << 16);                                  \
    vo.z = (vc[4] >> 16)     | (vc[5] & 0xFFFF0000u);                          \
    ve.w = (vc[6] & 0xFFFFu) | (vc[7] << 16);                                  \
    vo.w = (vc[6] >> 16)     | (vc[7] & 0xFFFF0000u);                          \
    *(uint4*)&Vt[B][vti0] = ve;                                                \
    *(uint4*)&Vt[B][vti1] = vo;                                                \
} while (0)

#define PREFETCH_TILE(KT) do {                                                 \
    const ushort* srcr = Hh + (size_t)((KT) * 64 + kr2) * 64 + db;             \
    pre0 = *(const short8*)srcr;                                               \
    pre1 = *(const short8*)(srcr + 64);                                        \
    _Pragma("unroll")                                                          \
    for (int j = 0; j < 8; ++j)                                                \
        vc[j] = *(const unsigned*)(Hh + (size_t)((KT) * 64 + kr8 + j) * 64 + d0); \
} while (0)

    #pragma unroll 1
    for (int half = 0; half < 2; ++half) {
        if (half) bar_lds();            // scratch reads done before restaging

        const int qt  = half ? p : (63 - p);
        const int q0  = qt * 32;
        const int wq  = q0 + qsub * 16; // this wave's q base
        const int nkt = (qt >> 1) + 1;  // # of 64-key tiles

        // Q fragments (B-operand: n=q=m, k=d), pre-scaled by log2(e)/8
        short8 qa[2];
        #pragma unroll
        for (int kt2 = 0; kt2 < 2; ++kt2) {
            short8 raw = *(const short8*)(Hh + (size_t)(wq + m) * 64 + kt2 * 32 + quad * 8);
            #pragma unroll
            for (int j = 0; j < 8; ++j)
                qa[kt2][j] = (short)f2bf(bf2f((ushort)raw[j]) * QSCALE);
        }

        floatx4 O[4] = {};              // O^T partial (khalf keys): d=mt*16+quad*4+r, q=m
        float lacc = 0.0f;

        short8 pre0, pre1;              // row-load prefetch (Ks)
        unsigned vc[8];                 // col-load prefetch (Vt)
        PREFETCH_TILE(0);
        STAGE_TILE(0);
        if (nkt > 1) PREFETCH_TILE(1);  // in flight across the barrier
        bar_lds();

        for (int kt = 0; kt < nkt; ++kt) {
            const int cur = kt & 1;

            // ---- S^T = K Q^T : this wave's 32 keys (khalf) x its 16 q ----
            floatx4 S[2] = {};
            #pragma unroll
            for (int kt2 = 0; kt2 < 2; ++kt2)
                #pragma unroll
                for (int mt2 = 0; mt2 < 2; ++mt2) {
                    const int row = khalf * 32 + mt2 * 16 + m;
                    const int col = (kt2 * 32 + quad * 8) ^ (((row >> 3) & 7) << 3);
                    short8 ka = *(const short8*)&Ks[cur][row * PK + col];
                    S[mt2] = MFMA16(ka, qa[kt2], S[mt2]);
                }

            // ---- exp2 + packed P write + l accumulate (own key-half) ----
            const int lim  = wq + m - kt * 64;
            const bool diag = (kt == nkt - 1);
            #pragma unroll
            for (int mt2 = 0; mt2 < 2; ++mt2) {
                const int kb = (khalf * 2 + mt2) * 16 + quad * 4;   // key-in-tile base
                float p0, p1, p2, p3;
                if (diag) {
                    p0 = (kb + 0 <= lim) ? exp2f(S[mt2][0]) : 0.0f;
                    p1 = (kb + 1 <= lim) ? exp2f(S[mt2][1]) : 0.0f;
                    p2 = (kb + 2 <= lim) ? exp2f(S[mt2][2]) : 0.0f;
                    p3 = (kb + 3 <= lim) ? exp2f(S[mt2][3]) : 0.0f;
                } else {
                    p0 = exp2f(S[mt2][0]);
                    p1 = exp2f(S[mt2][1]);
                    p2 = exp2f(S[mt2][2]);
                    p3 = exp2f(S[mt2][3]);
                }
                lacc += (p0 + p1) + (p2 + p3);
                uint2 pw;
                pw.x = cvt_pk_bf16(p0, p1);
                pw.y = cvt_pk_bf16(p2, p3);
                *(uint2*)&Psw[m * PK + kb] = pw;
            }

            // ---- O^T += V^T P^T over own 32 keys: 4 MFMAs (k=32) ----
            short8 pb = *(const short8*)&Psw[m * PK + khalf * 32 + quad * 8];
            #pragma unroll
            for (int mt = 0; mt < 4; ++mt) {
                short8 va = *(const short8*)
                    &Vt[cur][(mt * 16 + m) * PK + khalf * 32 + quad * 8];
                O[mt] = MFMA16(va, pb, O[mt]);
            }

            // ---- stage next tile into alternate buffer; prefetch kt+2 ----
            if (kt + 1 < nkt) {
                const int nxt = cur ^ 1;
                STAGE_TILE(nxt);
                if (kt + 2 < nkt) PREFETCH_TILE(kt + 2);
            }
            bar_lds();                  // ONE barrier per iteration
        }

        // ---- merge key-half partials (Ks[0] reused as scratch) ----
        lacc += __shfl_xor(lacc, 16);
        lacc += __shfl_xor(lacc, 32);
        if (khalf == 1) {
            #pragma unroll
            for (int mt = 0; mt < 4; ++mt)
                #pragma unroll
                for (int r = 0; r < 4; ++r) {
                    int d = mt * 16 + quad * 4 + r;
                    Om[(qsub * 64 + d) * 17 + m] = O[mt][r];
                }
            if (quad == 0) Lm[qsub * 16 + m] = lacc;
        }
        bar_lds();
        if (khalf == 0) {
            float linv = 1.0f / (lacc + Lm[qsub * 16 + m]);
            #pragma unroll
            for (int mt = 0; mt < 4; ++mt)
                #pragma unroll
                for (int r = 0; r < 4; ++r) {
                    int d = mt * 16 + quad * 4 + r;
                    float v = O[mt][r] + Om[(qsub * 64 + d) * 17 + m];
                    out[((size_t)bh * 64 + d) * NSEQ + q0 + qsub * 16 + m] = v * linv;
                }
        }
    }
#undef STAGE_TILE
#undef PREFETCH_TILE
}

extern "C" void kernel_launch(void* const* d_in, const int* in_sizes, int n_in,
                              void* d_out, int out_size, void* d_ws, size_t ws_size,
                              hipStream_t stream)
{
    (void)in_sizes; (void)n_in; (void)out_size; (void)ws_size;
    const float* x  = (const float*)d_in[0];
    const float* Wq = (const float*)d_in[1];
    float* out = (float*)d_out;

    ushort* hb = (ushort*)d_ws;                 // 6.29 MB (ws is 256 MiB)

    qkv_mfma<<<dim3(64, 12), dim3(256), 0, stream>>>(x, Wq, hb);
    attn_mfma<<<dim3(32, 24), dim3(256), 0, stream>>>(hb, out);
}

// Round 13
// 119.634 us; speedup vs baseline: 1.2514x; 1.2514x over previous
//
#include <hip/hip_runtime.h>
#include <math.h>

typedef __attribute__((ext_vector_type(8)))  short short8;    // 8 bf16 = 4 VGPRs
typedef __attribute__((ext_vector_type(4)))  float floatx4;   // 16x16 MFMA C/D
typedef __attribute__((ext_vector_type(16))) float floatx16;  // 32x32 MFMA C/D

#define MFMA16(a, b, c) __builtin_amdgcn_mfma_f32_16x16x32_bf16(a, b, c, 0, 0, 0)
#define MFMA32(a, b, c) __builtin_amdgcn_mfma_f32_32x32x16_bf16(a, b, c, 0, 0, 0)

constexpr int NSEQ = 2048;
constexpr int DIN  = 768;
constexpr int NH   = 12;
constexpr float QSCALE = 0.18033688011112042f;  // log2(e)/8

constexpr int PK = 72;   // 144 B rows, 16 B-aligned for b128

__device__ __forceinline__ ushort f2bf(float f) {   // RNE fp32 -> bf16
    unsigned u = __float_as_uint(f);
    u += 0x7FFF + ((u >> 16) & 1);
    return (ushort)(u >> 16);
}
__device__ __forceinline__ float bf2f(ushort u) {
    return __uint_as_float(((unsigned)u) << 16);
}
__device__ __forceinline__ unsigned cvt_pk_bf16(float lo, float hi) {
    unsigned r;
    asm("v_cvt_pk_bf16_f32 %0, %1, %2" : "=v"(r) : "v"(lo), "v"(hi));
    return r;
}
// pack 8 f32 -> 8 bf16 (RNE) with 4 instructions
__device__ __forceinline__ short8 pk8(float4 a, float4 b) {
    union { unsigned u[4]; short8 s; } r;
    r.u[0] = cvt_pk_bf16(a.x, a.y);
    r.u[1] = cvt_pk_bf16(a.z, a.w);
    r.u[2] = cvt_pk_bf16(b.x, b.y);
    r.u[3] = cvt_pk_bf16(b.z, b.w);
    return r.s;
}
// LDS-only barrier: orders ds ops across the block WITHOUT draining vmcnt.
__device__ __forceinline__ void bar_lds() {
    asm volatile("s_waitcnt lgkmcnt(0)" ::: "memory");
    __builtin_amdgcn_s_barrier();
}

// -----------------------------------------------------------------------------
// Kernel 1: h = x @ Wq^T, fused f32->bf16, DOUBLE-BUFFERED LDS (r10 verified).
// BM=64 x BN=64, grid (64,12) = 768 blocks, 3/CU. UNCHANGED.
// -----------------------------------------------------------------------------
__global__ __launch_bounds__(256, 3)
void qkv_mfma(const float* __restrict__ x, const float* __restrict__ Wq,
              ushort* __restrict__ h)
{
    __shared__ ushort As[2][64 * PK];
    __shared__ ushort Bs[2][64 * PK];

    const int tid  = threadIdx.x;
    const int w    = tid >> 6;
    const int lane = tid & 63;
    const int m    = lane & 15;
    const int quad = lane >> 4;
    const int r0   = blockIdx.x * 64;
    const int c0   = blockIdx.y * 64;
    const int mrow0 = (w & 1) * 32;
    const int ncol0 = (w >> 1) * 32;

    const int srow = tid >> 3;
    const int scol = (tid & 7) * 8;

    floatx4 C[2][2] = {};
    float4 arf[2][2], brf[2][2];

    #pragma unroll
    for (int i = 0; i < 2; ++i) {
        const float* ax = x  + (size_t)(r0 + srow + i * 32) * DIN + scol;
        const float* bx = Wq + (size_t)(c0 + srow + i * 32) * DIN + scol;
        arf[i][0] = ((const float4*)ax)[0]; arf[i][1] = ((const float4*)ax)[1];
        brf[i][0] = ((const float4*)bx)[0]; brf[i][1] = ((const float4*)bx)[1];
    }
    #pragma unroll
    for (int i = 0; i < 2; ++i) {
        *(short8*)&As[0][(srow + i * 32) * PK + scol] = pk8(arf[i][0], arf[i][1]);
        *(short8*)&Bs[0][(srow + i * 32) * PK + scol] = pk8(brf[i][0], brf[i][1]);
    }
    #pragma unroll
    for (int i = 0; i < 2; ++i) {
        const float* ax = x  + (size_t)(r0 + srow + i * 32) * DIN + 64 + scol;
        const float* bx = Wq + (size_t)(c0 + srow + i * 32) * DIN + 64 + scol;
        arf[i][0] = ((const float4*)ax)[0]; arf[i][1] = ((const float4*)ax)[1];
        brf[i][0] = ((const float4*)bx)[0]; brf[i][1] = ((const float4*)bx)[1];
    }
    bar_lds();

    for (int kk = 0; kk < 12; ++kk) {
        const int cur = kk & 1;

        #pragma unroll
        for (int kt2 = 0; kt2 < 2; ++kt2) {
            short8 a0 = *(const short8*)&As[cur][(mrow0 + m)      * PK + kt2 * 32 + quad * 8];
            short8 a1 = *(const short8*)&As[cur][(mrow0 + 16 + m) * PK + kt2 * 32 + quad * 8];
            short8 b0 = *(const short8*)&Bs[cur][(ncol0 + m)      * PK + kt2 * 32 + quad * 8];
            short8 b1 = *(const short8*)&Bs[cur][(ncol0 + 16 + m) * PK + kt2 * 32 + quad * 8];
            C[0][0] = MFMA16(a0, b0, C[0][0]);
            C[0][1] = MFMA16(a0, b1, C[0][1]);
            C[1][0] = MFMA16(a1, b0, C[1][0]);
            C[1][1] = MFMA16(a1, b1, C[1][1]);
        }

        if (kk + 1 < 12) {
            const int nxt = cur ^ 1;
            #pragma unroll
            for (int i = 0; i < 2; ++i) {
                *(short8*)&As[nxt][(srow + i * 32) * PK + scol] = pk8(arf[i][0], arf[i][1]);
                *(short8*)&Bs[nxt][(srow + i * 32) * PK + scol] = pk8(brf[i][0], brf[i][1]);
            }
            if (kk + 2 < 12) {
                const int k0 = (kk + 2) * 64;
                #pragma unroll
                for (int i = 0; i < 2; ++i) {
                    const float* ax = x  + (size_t)(r0 + srow + i * 32) * DIN + k0 + scol;
                    const float* bx = Wq + (size_t)(c0 + srow + i * 32) * DIN + k0 + scol;
                    arf[i][0] = ((const float4*)ax)[0]; arf[i][1] = ((const float4*)ax)[1];
                    brf[i][0] = ((const float4*)bx)[0]; brf[i][1] = ((const float4*)bx)[1];
                }
            }
            bar_lds();
        }
    }

    #pragma unroll
    for (int mt = 0; mt < 2; ++mt)
        #pragma unroll
        for (int nt = 0; nt < 2; ++nt) {
            int cg = c0 + ncol0 + nt * 16 + m;
            int head = cg >> 6, d = cg & 63;
            #pragma unroll
            for (int r = 0; r < 4; ++r) {
                int rg = r0 + mrow0 + mt * 16 + quad * 4 + r;
                int b = rg >> 11, q = rg & 2047;
                h[((size_t)(b * NH + head) * NSEQ + q) * 64 + d] = f2bf(C[mt][nt][r]);
            }
        }
}

// -----------------------------------------------------------------------------
// Kernel 2: causal flash attention — 32x32 MFMA, in-register P, 2 waves x 32 q.
// LDS-pipe model (fits r1..r12): r10 spent ~960+250 cyc/block-iter on LDS ops;
// this cuts to ~420: Ps GONE (cvt_pk + v_permlane32_swap builds PV's B-operand
// in registers), ka/va reads halved (32x32 fragments), Vt staged as b64 4-key
// packs, Ks writes additive-swizzled (colblk -> (colblk + 2*(key&7))&7).
// Bank audit (all exactly-minimum, conflict-free):
//  Ks write g=(4(k'&1)+3j+cc)%8: 8 lanes/grp. Ks read g=(3(col&7)+2s+hi)%8: 8.
//  Vt write g2=(2i+k')%16: 4 lanes/grp (b64 min). Vt read g=(col+hi+c)%8: 8.
// Layouts: 32x32x16 A/B: row|col=l&31, k=(l>>5)*8+j. C/D (m74-verified):
// col=l&31, row=(reg&3)+8*(reg>>2)+4*(l>>5).
// B-frag derivation: lane needs keys hi*8+j of a 16-slice; it holds keys
// 4hi+{0..3},8+4hi+{0..3} as cvt_pk dwords a0,a1,a2,a3; permlane32_swap(a0,a2)
// and (a1,a3) yield exactly {dw0,dw1,dw2,dw3} (lane l<->l+32 = same q ✓).
// Grid (64,24)=1536 blocks, 128 thr, qt alternation (r1/r11-verified balance).
// -----------------------------------------------------------------------------
__global__ __launch_bounds__(128, 3)
void attn_mfma(const ushort* __restrict__ h, float* __restrict__ out)
{
    __shared__ ushort Ks[64 * PK];      // [key][d]  additive-swizzled 16B blocks
    __shared__ ushort Vt[64 * PK];      // [d][key]  linear

    const int tid  = threadIdx.x;
    const int w    = tid >> 6;          // wave = key-half 0/1
    const int lane = tid & 63;
    const int col  = lane & 31;         // q (and fragment row) index
    const int hi   = lane >> 5;

    const int xi = blockIdx.x;          // 0..63
    const int bh = blockIdx.y;          // 0..23
    const int qt = ((bh >> 2) & 1) ? xi : (63 - xi);   // per-CU balance
    const int q0 = qt * 32;
    const int nkt = (qt >> 1) + 1;      // # of 64-key tiles
    const ushort* __restrict__ Hh = h + (size_t)bh * NSEQ * 64;

    // staging mapping: thread stages 4 key rows x one 8-ushort d-block
    const int kp = (tid & 15) * 4;      // key rows kp..kp+3
    const int cc = tid >> 4;            // d-block 0..7

    // Q fragments (B-operand of S^T): B[k=d][n=q]: lane col=q, k=hi*8+j
    short8 qa[4];
    #pragma unroll
    for (int s = 0; s < 4; ++s) {
        short8 raw = *(const short8*)(Hh + (size_t)(q0 + col) * 64 + s * 16 + hi * 8);
        #pragma unroll
        for (int j = 0; j < 8; ++j)
            qa[s][j] = (short)f2bf(bf2f((ushort)raw[j]) * QSCALE);
    }

    floatx16 O[2] = {};                 // O^T: d = dt*32 + rowfn(reg,hi), q = col
    float lacc = 0.0f;

    short8 fr[4];                       // prefetched key rows kp..kp+3, block cc
#define PREFETCH(KT) do {                                                      \
    const ushort* s_ = Hh + ((size_t)(KT) * 64 + kp) * 64 + cc * 8;            \
    fr[0] = *(const short8*)s_;                                                \
    fr[1] = *(const short8*)(s_ + 64);                                         \
    fr[2] = *(const short8*)(s_ + 128);                                        \
    fr[3] = *(const short8*)(s_ + 192);                                        \
} while (0)

    PREFETCH(0);

    for (int kt = 0; kt < nkt; ++kt) {
        bar_lds();                      // prev iter's ka/va reads complete

        // ---- stage: Ks (4 x b128, swizzled) + Vt (8 x b64, 4-key packs) ----
        #pragma unroll
        for (int j = 0; j < 4; ++j) {
            int ky = kp + j;
            *(short8*)&Ks[ky * PK + (((cc + 2 * (ky & 7)) & 7) << 3)] = fr[j];
        }
        {
            union { short8 v; ushort u[8]; } f0, f1, f2, f3;
            f0.v = fr[0]; f1.v = fr[1]; f2.v = fr[2]; f3.v = fr[3];
            #pragma unroll
            for (int i = 0; i < 8; ++i) {
                uint2 dw;
                dw.x = (unsigned)f0.u[i] | ((unsigned)f1.u[i] << 16);
                dw.y = (unsigned)f2.u[i] | ((unsigned)f3.u[i] << 16);
                *(uint2*)&Vt[(cc * 8 + i) * PK + kp] = dw;
            }
        }
        if (kt + 1 < nkt) PREFETCH(kt + 1);   // in flight across barrier
        bar_lds();                      // staging visible

        // ---- S^T = K Q^T : wave's 32 keys x 32 q, accumulate over 4 d-slices
        floatx16 S = {};
        #pragma unroll
        for (int s = 0; s < 4; ++s) {
            int key = w * 32 + col;
            short8 ka = *(const short8*)
                &Ks[key * PK + (((s * 2 + hi + 2 * (col & 7)) & 7) << 3)];
            S = MFMA32(ka, qa[s], S);
        }

        // ---- softmax piece + in-register P -> PV B-fragments ----
        const bool diag = (kt == nkt - 1);
        const int kbase = kt * 64 + w * 32;
        const int qabs  = q0 + col;
        unsigned bfr[2][4];
        #pragma unroll
        for (int h2 = 0; h2 < 2; ++h2) {
            float p[8];
            #pragma unroll
            for (int j = 0; j < 8; ++j) {
                const int reg = h2 * 8 + j;
                const int kl  = (reg & 3) + 8 * (reg >> 2) + 4 * hi;
                float pv = exp2f(S[reg]);
                if (diag && (kbase + kl > qabs)) pv = 0.0f;
                p[j] = pv;
                lacc += pv;
            }
            unsigned a0 = cvt_pk_bf16(p[0], p[1]);
            unsigned a1 = cvt_pk_bf16(p[2], p[3]);
            unsigned a2 = cvt_pk_bf16(p[4], p[5]);
            unsigned a3 = cvt_pk_bf16(p[6], p[7]);
            asm volatile("v_permlane32_swap_b32 %0, %1" : "+v"(a0), "+v"(a2));
            asm volatile("v_permlane32_swap_b32 %0, %1" : "+v"(a1), "+v"(a3));
            bfr[h2][0] = a0; bfr[h2][1] = a1; bfr[h2][2] = a2; bfr[h2][3] = a3;
        }

        // ---- O^T += V^T P^T : 2 d-tiles x 2 key-16-slices ----
        #pragma unroll
        for (int h2 = 0; h2 < 2; ++h2) {
            union { unsigned u[4]; short8 v; } pb;
            pb.u[0] = bfr[h2][0]; pb.u[1] = bfr[h2][1];
            pb.u[2] = bfr[h2][2]; pb.u[3] = bfr[h2][3];
            #pragma unroll
            for (int dt = 0; dt < 2; ++dt) {
                short8 va = *(const short8*)
                    &Vt[(dt * 32 + col) * PK + w * 32 + h2 * 16 + hi * 8];
                O[dt] = MFMA32(va, pb.v, O[dt]);
            }
        }
    }
#undef PREFETCH

    // ---- combine hi-halves of l (lanes l, l+32 share q) ----
    lacc += __shfl_xor(lacc, 32);

    // ---- cross-wave merge via scratch aliased on Ks ----
    float* OmA = (float*)&Ks[0];        // wave0's dt=1 partial [32][33]
    float* OmB = OmA + 32 * 33;         // wave1's dt=0 partial [32][33]
    float* Lg  = OmB + 32 * 33;         // [2][32]

    bar_lds();                          // all Ks/Vt reads done
    {
        float* Om = (w == 0) ? OmA : OmB;
        #pragma unroll
        for (int reg = 0; reg < 16; ++reg) {
            const int dl = (reg & 3) + 8 * (reg >> 2) + 4 * hi;
            Om[dl * 33 + col] = (w == 0) ? O[1][reg] : O[0][reg];
        }
        if (hi == 0) Lg[w * 32 + col] = lacc;
    }
    bar_lds();
    {
        const float linv = 1.0f / (Lg[col] + Lg[32 + col]);
        float* Om = (w == 0) ? OmB : OmA;
        #pragma unroll
        for (int reg = 0; reg < 16; ++reg) {
            const int dl = (reg & 3) + 8 * (reg >> 2) + 4 * hi;
            const int d  = w * 32 + dl;
            const float v = ((w == 0) ? O[0][reg] : O[1][reg]) + Om[dl * 33 + col];
            out[((size_t)bh * 64 + d) * NSEQ + q0 + col] = v * linv;
        }
    }
}

extern "C" void kernel_launch(void* const* d_in, const int* in_sizes, int n_in,
                              void* d_out, int out_size, void* d_ws, size_t ws_size,
                              hipStream_t stream)
{
    (void)in_sizes; (void)n_in; (void)out_size; (void)ws_size;
    const float* x  = (const float*)d_in[0];
    const float* Wq = (const float*)d_in[1];
    float* out = (float*)d_out;

    ushort* hb = (ushort*)d_ws;                 // 6.29 MB (ws is 256 MiB)

    qkv_mfma<<<dim3(64, 12), dim3(256), 0, stream>>>(x, Wq, hb);
    attn_mfma<<<dim3(64, 24), dim3(128), 0, stream>>>(hb, out);
}